// Round 1
// baseline (11.674 us; speedup 1.0000x reference)
//
#include <hip/hip_runtime.h>

// CenterLoss collapses algebraically: after masking, only distmat[b, label_b]
// survives per row; every other entry is 0 -> clamps to 1e-12.
// loss = (1/B) * sum_b clip(||x_b - c_{label_b}||^2, 1e-12, 1e12) + (C-1)*1e-12

#define BATCH 1024
#define FEAT_DIM 128
#define NUM_CLASSES 100000

// One wave (64 lanes) per row; each lane covers 2 of the 128 features via a
// float2 load (fully coalesced, 512B per wave per matrix row).
__global__ void center_row_dist_kernel(const float* __restrict__ x,
                                       const int* __restrict__ label,
                                       const float* __restrict__ centers,
                                       float* __restrict__ row_out) {
    const int gtid      = blockIdx.x * blockDim.x + threadIdx.x;
    const int wave      = gtid >> 6;
    const int lane      = threadIdx.x & 63;
    const int num_waves = (gridDim.x * blockDim.x) >> 6;

    for (int row = wave; row < BATCH; row += num_waves) {
        const int lbl = label[row];  // wave-uniform scalar load
        const float2 xv = *reinterpret_cast<const float2*>(x + (size_t)row * FEAT_DIM + lane * 2);
        const float2 cv = *reinterpret_cast<const float2*>(centers + (size_t)lbl * FEAT_DIM + lane * 2);
        const float d0 = xv.x - cv.x;
        const float d1 = xv.y - cv.y;
        float s = d0 * d0 + d1 * d1;

        // 64-lane butterfly reduce
        #pragma unroll
        for (int off = 32; off > 0; off >>= 1)
            s += __shfl_xor(s, off, 64);

        if (lane == 0) {
            // clamp AFTER selecting the surviving entry (faithful to reference)
            s = fminf(fmaxf(s, 1e-12f), 1e12f);
            row_out[row] = s;
        }
    }
}

// Deterministic single-block reduction of the 1024 per-row values.
__global__ void center_loss_reduce_kernel(const float* __restrict__ row_vals,
                                          float* __restrict__ out) {
    __shared__ float sm[256];
    const int tid = threadIdx.x;
    float s = row_vals[tid] + row_vals[tid + 256] + row_vals[tid + 512] + row_vals[tid + 768];
    sm[tid] = s;
    __syncthreads();
    #pragma unroll
    for (int off = 128; off >= 1; off >>= 1) {
        if (tid < off) sm[tid] += sm[tid + off];
        __syncthreads();
    }
    if (tid == 0) {
        // masked-off zeros: B*(C-1) entries clamp to 1e-12; /B -> (C-1)*1e-12
        const float masked_contrib = (float)(NUM_CLASSES - 1) * 1e-12f;
        out[0] = sm[0] / (float)BATCH + masked_contrib;
    }
}

extern "C" void kernel_launch(void* const* d_in, const int* in_sizes, int n_in,
                              void* d_out, int out_size, void* d_ws, size_t ws_size,
                              hipStream_t stream) {
    const float* x       = (const float*)d_in[0];
    const int*   label   = (const int*)d_in[1];
    const float* centers = (const float*)d_in[2];
    float*       out     = (float*)d_out;
    float*       ws      = (float*)d_ws;  // needs BATCH floats = 4 KB

    // 64 blocks x 256 threads = 256 waves; 4 rows per wave.
    center_row_dist_kernel<<<64, 256, 0, stream>>>(x, label, centers, ws);
    center_loss_reduce_kernel<<<1, 256, 0, stream>>>(ws, out);
}